// Round 1
// baseline (101.594 us; speedup 1.0000x reference)
//
#include <hip/hip_runtime.h>

// RoIAlign forward (SR=2, aligned). feat [4,256,100,100] f32, rois [512,5], out [512,256,7,7].
// v2: block = (image, channel QUAD). One block per CU (LDS 163200B forces it).
// Two interleaved pair-planes double-buffer: stage pair0 -> issue pair1 global
// loads into registers (async-STAGE split, T14) -> record loop on buf0 while
// pair1's HBM traffic is in flight -> ds_write buf1 -> record loop on buf1.
// Rows padded 100->102 pairs (816B stride) so bank-pair = (6r+x) mod 16,
// killing the dRow==0 (mod 4) conflict class of the old 800B stride.
// Setup kernel precomputes per-(roi,bin) 32B records grouped by image
// (row offsets now pre-multiplied by the padded stride).

#define FEAT_C 256
#define FEAT_H 100
#define FEAT_W 100
#define HW     10000
#define NROI   512
#define NBINS  49
#define IMG_N  4

#define REC_BYTES  32
#define IMG_STRIDE (NROI * NBINS * REC_BYTES)   // worst case: all rois in one image
#define CNT_OFF    (IMG_N * IMG_STRIDE)         // counts[4] after record area

#define ROWP   102                  // padded row stride in pixel-PAIRS (816 B)
#define PLANEP (ROWP * FEAT_H)      // 10200 pairs = 81600 B per pair-plane

typedef float f32x2 __attribute__((ext_vector_type(2)));

// Matches ref: v=max(v,0); l=floor(v) clamped at 99; fr=v-l_clamped.
__device__ __forceinline__ void samp_geo(float s, float bsz, int idx, int sr_i,
                                         int& lo, float& fr) {
    float v = s + bsz * ((float)idx + ((float)sr_i + 0.5f) * 0.5f);
    v = fmaxf(v, 0.0f);
    int l = (int)v;                   // v>=0: trunc == floor == astype(int32)
    if (l > FEAT_H - 1) l = FEAT_H - 1;
    fr = v - (float)l;
    lo = l;
}

// ---- Setup: one block per roi; ballot-computed per-image slot (no atomics).
__global__ __launch_bounds__(64) void roialign_setup(
    const float* __restrict__ rois, char* __restrict__ ws)
{
    const int k    = blockIdx.x;
    const int lane = threadIdx.x;
    const float* r = rois + k * 5;
    const int bk   = (int)r[0];

    int slot = 0, total = 0;
    for (int i = 0; i < NROI; i += 64) {
        int bi = (int)rois[(i + lane) * 5];
        unsigned long long m = __ballot(bi == bk);
        total += __popcll(m);
        int rel = k - i;
        unsigned long long lt = rel <= 0 ? 0ull
                              : (rel >= 64 ? ~0ull : ((1ull << rel) - 1ull));
        slot += __popcll(m & lt);
    }
    if (lane == 0) ((int*)(ws + CNT_OFF))[bk] = total;   // same-value dup writes ok

    if (lane < NBINS) {
        const float sw = r[1] * 0.25f - 0.5f, sh = r[2] * 0.25f - 0.5f;
        const float ew = r[3] * 0.25f - 0.5f, eh = r[4] * 0.25f - 0.5f;
        const float bh = (eh - sh) * (1.0f / 7.0f);
        const float bw = (ew - sw) * (1.0f / 7.0f);
        const int ph = (lane * 37) >> 8;        // lane/7 (exact, lane<49)
        const int pw = lane - ph * 7;
        int ylA, ylB, xl0, xl1; float lyA, lyB, lx0, lx1;
        samp_geo(sh, bh, ph, 0, ylA, lyA);
        samp_geo(sh, bh, ph, 1, ylB, lyB);
        samp_geo(sw, bw, pw, 0, xl0, lx0);
        samp_geo(sw, bw, pw, 1, xl1, lx1);
        if (xl0 >= FEAT_W - 1) lx0 = 0.0f;      // x border: xh==xl -> kill hi weight
        if (xl1 >= FEAT_W - 1) lx1 = 0.0f;      //   (OOB pair lands in zeroed pad)
        int yhA = min(ylA + 1, FEAT_H - 1), yhB = min(ylB + 1, FEAT_H - 1);
        uint4 a, b2;
        a.x  = (unsigned)(ylA * ROWP) | ((unsigned)(yhA * ROWP) << 16);  // padded row-pair offs
        a.y  = (unsigned)(ylB * ROWP) | ((unsigned)(yhB * ROWP) << 16);
        a.z  = (unsigned)(xl0 * 4)   | ((unsigned)(xl1 * 4)   << 16);
        a.w  = __float_as_uint(lyA);
        b2.x = __float_as_uint(lyB);
        b2.y = __float_as_uint(lx0);
        b2.z = __float_as_uint(lx1);
        b2.w = (unsigned)(k * (FEAT_C * NBINS) + lane);  // out idx (roi+bin part)
        char* dst = ws + bk * IMG_STRIDE + (slot * NBINS + lane) * REC_BYTES;
        *(uint4*)dst        = a;
        *(uint4*)(dst + 16) = b2;
    }
}

// Interleave-write one float4 chunk (4 pixels, both channels) into a padded plane.
__device__ __forceinline__ void wr_pairs(f32x2* buf, int t, float4 A, float4 B) {
    const int r = (t * 1311) >> 15;             // t/25 exact for t<2500
    const int p = ROWP * r + 4 * (t - 25 * r);  // p even -> 16B aligned
    float4* d = (float4*)&buf[p];
    d[0] = make_float4(A.x, B.x, A.y, B.y);
    d[1] = make_float4(A.z, B.z, A.w, B.w);
}

// ---- Main: block = (img, channel quad); double-buffered interleaved pair-planes.
__global__ __launch_bounds__(1024, 4) void roialign_main(
    const float* __restrict__ feat, const char* __restrict__ ws,
    float* __restrict__ out)
{
    __shared__ __align__(16) f32x2 s_buf[2][PLANEP];   // 163200 B -> 1 block/CU

    const int bid = blockIdx.x;
    const int img = bid & 3;
    const int q   = bid >> 2;                          // channel quad 0..63
    const int tid = threadIdx.x;

    const float* c0 = feat + (size_t)(img * FEAT_C + 4 * q) * HW;
    const float* c1 = c0 + HW;

    // Stage pair0 (channels 4q, 4q+1) interleaved+padded.
    for (int t = tid; t < HW / 4; t += 1024) {         // 2500 float4 chunks
        float4 A = ((const float4*)c0)[t];
        float4 B = ((const float4*)c1)[t];
        wr_pairs(s_buf[0], t, A, B);
    }
    if (tid < FEAT_H) {                                // zero border-tap pads (weight-0 reads)
        s_buf[0][ROWP * tid + FEAT_W] = f32x2{0.0f, 0.0f};
        s_buf[1][ROWP * tid + FEAT_W] = f32x2{0.0f, 0.0f};
    }

    int cnt = ((const int*)(ws + CNT_OFF))[img];
    const int nrec = (cnt < 0 || cnt > NROI) ? 0 : cnt * NBINS;   // poison-safe
    const char* rb = ws + img * IMG_STRIDE;

    // Early-issue pair1 (channels 4q+2, 4q+3) global loads into registers:
    // their HBM latency hides under the buf0 record loop (async-STAGE split).
    const float4* c2v = (const float4*)(c0 + 2 * HW);
    const float4* c3v = (const float4*)(c0 + 3 * HW);
    const int t1 = tid + 1024, t2 = tid + 2048;        // t1 < 2500 always
    float4 sa0 = c2v[tid], sb0 = c3v[tid];
    float4 sa1 = c2v[t1],  sb1 = c3v[t1];
    float4 sa2, sb2;
    if (t2 < HW / 4) { sa2 = c2v[t2]; sb2 = c3v[t2]; }

    auto rec_loop = [&](const f32x2* sbase, float* ocp) {
        int   idx = tid;
        uint4 ra, rk;
        if (idx < nrec) {                              // prefetch record 0
            const char* p = rb + (size_t)idx * REC_BYTES;
            ra = *(const uint4*)p;
            rk = *(const uint4*)(p + 16);
        }
        __syncthreads();                               // publishes LDS plane

        while (idx < nrec) {
            const uint4 a = ra, b = rk;
            const int nidx = idx + 1024;
            if (nidx < nrec) {                         // prefetch next record
                const char* p = rb + (size_t)nidx * REC_BYTES;
                ra = *(const uint4*)p;
                rk = *(const uint4*)(p + 16);
            }

            const char* base = (const char*)sbase;
            // Padded-row-pair offsets -> interleaved byte offsets.
            const int oAl = (a.x & 0xffff) * 8, oAh = (a.x >> 16) * 8;
            const int oBl = (a.y & 0xffff) * 8, oBh = (a.y >> 16) * 8;
            const int x0  = (a.z & 0xffff) * 2, x1  = (a.z >> 16) * 2;
            const float lyA = __uint_as_float(a.w), hyA = 1.0f - lyA;
            const float lyB = __uint_as_float(b.x), hyB = 1.0f - lyB;
            const float lx0 = __uint_as_float(b.y), hx0 = 1.0f - lx0;
            const float lx1 = __uint_as_float(b.z), hx1 = 1.0f - lx1;

            // 8 ds_read2_b64: each serves BOTH channels (adjacent f32x2 pair).
            const f32x2* pAl0 = (const f32x2*)(base + oAl + x0);
            const f32x2* pAl1 = (const f32x2*)(base + oAl + x1);
            const f32x2* pAh0 = (const f32x2*)(base + oAh + x0);
            const f32x2* pAh1 = (const f32x2*)(base + oAh + x1);
            const f32x2* pBl0 = (const f32x2*)(base + oBl + x0);
            const f32x2* pBl1 = (const f32x2*)(base + oBl + x1);
            const f32x2* pBh0 = (const f32x2*)(base + oBh + x0);
            const f32x2* pBh1 = (const f32x2*)(base + oBh + x1);

            f32x2 sAl = pAl0[0] * hx0 + pAl0[1] * lx0 + pAl1[0] * hx1 + pAl1[1] * lx1;
            f32x2 sAh = pAh0[0] * hx0 + pAh0[1] * lx0 + pAh1[0] * hx1 + pAh1[1] * lx1;
            f32x2 sBl = pBl0[0] * hx0 + pBl0[1] * lx0 + pBl1[0] * hx1 + pBl1[1] * lx1;
            f32x2 sBh = pBh0[0] * hx0 + pBh0[1] * lx0 + pBh1[0] * hx1 + pBh1[1] * lx1;
            f32x2 acc = (sAl * hyA + sAh * lyA + sBl * hyB + sBh * lyB) * 0.25f;

            float* o = ocp + b.w;
            o[0]     = acc.x;                          // channel base
            o[NBINS] = acc.y;                          // channel base+1
            idx = nidx;
        }
    };

    // Loop 1: channels 4q, 4q+1 from buf0 (pair1 HBM traffic in flight).
    rec_loop(s_buf[0], out + (size_t)(4 * q) * NBINS);

    // Drain pair1 loads (compiler inserts vmcnt via reg deps) and write buf1.
    // buf0 readers may still be in-flight on other threads: disjoint LDS, no race.
    wr_pairs(s_buf[1], tid, sa0, sb0);
    wr_pairs(s_buf[1], t1,  sa1, sb1);
    if (t2 < HW / 4) wr_pairs(s_buf[1], t2, sa2, sb2);

    // Loop 2: channels 4q+2, 4q+3 from buf1 (rec_loop's barrier orders the writes).
    rec_loop(s_buf[1], out + (size_t)(4 * q + 2) * NBINS);
}

extern "C" void kernel_launch(void* const* d_in, const int* in_sizes, int n_in,
                              void* d_out, int out_size, void* d_ws, size_t ws_size,
                              hipStream_t stream) {
    const float* feat = (const float*)d_in[0];
    const float* rois = (const float*)d_in[1];
    float*       outp = (float*)d_out;
    roialign_setup<<<dim3(NROI), dim3(64), 0, stream>>>(rois, (char*)d_ws);
    roialign_main<<<dim3(IMG_N * (FEAT_C / 4)), dim3(1024), 0, stream>>>(
        feat, (const char*)d_ws, outp);
}